// Round 1
// 238.566 us; speedup vs baseline: 1.0180x; 1.0180x over previous
//
#include <hip/hip_runtime.h>

#define N_NODES 100000
#define N_EDGES 1600000
#define NBKT 196          // ceil(100000 / 512)
#define BKT_SHIFT 9
#define BKT_MASK 511
#define NT_TILES 6250     // N_NODES / 16

typedef __attribute__((ext_vector_type(8))) short short8;
typedef __attribute__((ext_vector_type(4))) float float4v;

__device__ __forceinline__ unsigned short f2bf(float f) {  // RNE
  unsigned u = __float_as_uint(f);
  return (unsigned short)((u + 0x7fffu + ((u >> 16) & 1u)) >> 16);
}
__device__ __forceinline__ float bflo(unsigned d) { return __uint_as_float(d << 16); }
__device__ __forceinline__ float bfhi(unsigned d) { return __uint_as_float(d & 0xffff0000u); }

// ---- binning: edges grouped by 512-node dst bucket -------------------------

__global__ void kA_count(const int* __restrict__ dst, int* __restrict__ blkCnt) {
  __shared__ int hist[NBKT];
  for (int t = threadIdx.x; t < NBKT; t += 256) hist[t] = 0;
  __syncthreads();
  const int chunk = (N_EDGES + gridDim.x - 1) / gridDim.x;
  const int e0 = blockIdx.x * chunk;
  const int e1 = min(e0 + chunk, N_EDGES);
  for (int e = e0 + threadIdx.x; e < e1; e += 256)
    atomicAdd(&hist[dst[e] >> BKT_SHIFT], 1);
  __syncthreads();
  for (int t = threadIdx.x; t < NBKT; t += 256)
    blkCnt[t * 256 + blockIdx.x] = hist[t];
}

__global__ void kA_scan1(int* __restrict__ blkCnt, int* __restrict__ bktTot) {
  const int b = blockIdx.x;
  const int tid = threadIdx.x, lane = tid & 63, w = tid >> 6;
  int v = blkCnt[b * 256 + tid];
  int inc = v;
  #pragma unroll
  for (int d = 1; d < 64; d <<= 1) { int y = __shfl_up(inc, d); if (lane >= d) inc += y; }
  __shared__ int wtot[4];
  if (lane == 63) wtot[w] = inc;
  __syncthreads();
  int base = 0;
  for (int j = 0; j < w; j++) base += wtot[j];
  blkCnt[b * 256 + tid] = base + inc - v;
  if (tid == 255) bktTot[b] = base + inc;
}

__global__ void kA_scan2(const int* __restrict__ bktTot, int* __restrict__ bktStart) {
  int lane = threadIdx.x;
  int running = 0;
  for (int base = 0; base < NBKT; base += 64) {
    int i = base + lane;
    int v = (i < NBKT) ? bktTot[i] : 0;
    int inc = v;
    #pragma unroll
    for (int d = 1; d < 64; d <<= 1) { int y = __shfl_up(inc, d); if (lane >= d) inc += y; }
    if (i < NBKT) bktStart[i] = running + inc - v;
    running += __shfl(inc, 63);
  }
}

__global__ void kA_scatter(const int* __restrict__ src, const int* __restrict__ dst,
                           const int* __restrict__ blkCnt, const int* __restrict__ bktStart,
                           int* __restrict__ binned) {
  __shared__ int curb[NBKT];
  for (int t = threadIdx.x; t < NBKT; t += 256)
    curb[t] = bktStart[t] + blkCnt[t * 256 + blockIdx.x];
  __syncthreads();
  const int chunk = (N_EDGES + gridDim.x - 1) / gridDim.x;
  const int e0 = blockIdx.x * chunk;
  const int e1 = min(e0 + chunk, N_EDGES);
  for (int e = e0 + threadIdx.x; e < e1; e += 256) {
    int d = dst[e];
    int s = src[e];
    int b = d >> BKT_SHIFT;
    int p = atomicAdd(&curb[b], 1);
    binned[p] = s | ((d & BKT_MASK) << 17);   // src:17 bits | dlocal:9 bits
  }
}

// ---- merged counting sort: hist + scan -> off, place -> esrc (one launch) --

__global__ void k_sort(const int* __restrict__ binned, const int* __restrict__ bktStart,
                       const int* __restrict__ bktTot,
                       int* __restrict__ off, int* __restrict__ esrc) {
  const int b = blockIdx.x;
  const int tid = threadIdx.x, lane = tid & 63, w = tid >> 6;
  __shared__ int cnt[512];
  __shared__ int pos[512];
  cnt[tid] = 0; cnt[tid + 256] = 0;
  __syncthreads();
  const int s0 = bktStart[b], ne = bktTot[b];
  for (int i = tid; i < ne; i += 256)
    atomicAdd(&cnt[binned[s0 + i] >> 17], 1);
  __syncthreads();
  // scan 512 counters: thread t owns nodes 2t, 2t+1
  int c0 = cnt[2 * tid], c1 = cnt[2 * tid + 1];
  int v = c0 + c1;
  int inc = v;
  #pragma unroll
  for (int d = 1; d < 64; d <<= 1) { int y = __shfl_up(inc, d); if (lane >= d) inc += y; }
  __shared__ int wtot[4];
  if (lane == 63) wtot[w] = inc;
  __syncthreads();
  int base = s0;
  for (int j = 0; j < w; j++) base += wtot[j];
  int ex = base + inc - v;  // global edge offset of node (b<<9)+2t
  pos[2 * tid] = ex;
  pos[2 * tid + 1] = ex + c0;
  int n0 = (b << BKT_SHIFT) + 2 * tid;
  if (n0 < N_NODES)     off[n0] = ex;
  if (n0 + 1 < N_NODES) off[n0 + 1] = ex + c0;
  if (b == NBKT - 1 && tid == 0) off[N_NODES] = N_EDGES;
  __syncthreads();
  // place (second binned read is L2-warm; esrc writes bucket-local)
  for (int i = tid; i < ne; i += 256) {
    int pe = binned[s0 + i];
    int p = atomicAdd(&pos[pe >> 17], 1);
    esrc[p] = pe & 0x1FFFF;
  }
}

// ---- merged: f32->bf16 feature cvt + weight pre-swizzle (one launch) -------

__global__ void k_prep(const float* __restrict__ in, unsigned short* __restrict__ outb,
                       const float* __restrict__ W0, const float* __restrict__ W1,
                       const float* __restrict__ W2, const float* __restrict__ W3,
                       unsigned short* __restrict__ F) {
  if (blockIdx.x < NT_TILES) {
    // cvt: 6250 blocks x 256 threads x float4 == exactly N_NODES*64 floats
    int i = blockIdx.x * 256 + threadIdx.x;
    float4 v = ((const float4*)in)[i];
    unsigned d0 = ((unsigned)f2bf(v.y) << 16) | f2bf(v.x);
    unsigned d1 = ((unsigned)f2bf(v.w) << 16) | f2bf(v.z);
    ((uint2*)outb)[i] = make_uint2(d0, d1);
    return;
  }
  // weight pre-swizzle into MFMA B-fragment order (4 trailing blocks)
  if (threadIdx.x >= 64) return;
  const int wsel = blockIdx.x - NT_TILES;
  const float* W = (wsel == 0) ? W0 : (wsel == 1) ? W1 : (wsel == 2) ? W2 : W3;
  unsigned short* out = F + wsel * 4096;
  int lane = threadIdx.x;
  int col = lane & 15, kr = lane >> 4;
  #pragma unroll
  for (int kc = 0; kc < 2; kc++)
    #pragma unroll
    for (int nt = 0; nt < 4; nt++) {
      unsigned d[4];
      #pragma unroll
      for (int jj = 0; jj < 4; jj++) {
        float w0 = W[(kc * 32 + kr * 8 + 2 * jj)     * 64 + nt * 16 + col];
        float w1 = W[(kc * 32 + kr * 8 + 2 * jj + 1) * 64 + nt * 16 + col];
        d[jj] = ((unsigned)f2bf(w1) << 16) | f2bf(w0);
      }
      uint4* p = (uint4*)(out + ((kc * 4 + nt) * 64 + lane) * 8);
      *p = make_uint4(d[0], d[1], d[2], d[3]);
    }
}

// ---- fused per-layer: mean-aggregate 16 nodes -> LDS -> MFMA transform -----
// out = self@Ws + agg@Wn + b ; optional ReLU; out as bf16 (layer1) or f32 (layer2)

template <bool RELU, bool OUT_BF>
__global__ void k_fused(const unsigned short* __restrict__ featb,
                        const int* __restrict__ off, const int* __restrict__ esrc,
                        const unsigned short* __restrict__ wfS,
                        const unsigned short* __restrict__ wfN,
                        const float* __restrict__ bias,
                        float* __restrict__ outf, unsigned short* __restrict__ outb) {
  // per-wave 16x64 bf16 agg tile, XOR-swizzled in 16B blocks:
  // row j, block b stored at slot b^(j&7)  -> conflict-free b128 writes & reads
  __shared__ unsigned short aggl[4][16 * 64];
  const int tid = threadIdx.x;
  const int lane = tid & 63;
  const int wslot = tid >> 6;
  const int t = (blockIdx.x * blockDim.x + tid) >> 6;   // one 16-node tile per wave
  if (t >= NT_TILES) return;

  unsigned short* lw = &aggl[wslot][0];
  const int r = lane >> 3;
  const int c = lane & 7;

  // ---- agg phase: 16 nodes serially (R6-proven 8x8 gather/reduce) ----
  int o1 = off[t * 16];
  for (int j = 0; j < 16; ++j) {
    const int o0 = o1;
    o1 = off[t * 16 + j + 1];
    float acc[8];
    #pragma unroll
    for (int q = 0; q < 8; q++) acc[q] = 0.f;

    int i = o0;
    for (; i + 16 <= o1; i += 16) {
      int sA = esrc[i + r];
      int sB = esrc[i + 8 + r];
      uint4 vA = *(const uint4*)(featb + sA * 64 + c * 8);
      uint4 vB = *(const uint4*)(featb + sB * 64 + c * 8);
      acc[0] += bflo(vA.x); acc[1] += bfhi(vA.x);
      acc[2] += bflo(vA.y); acc[3] += bfhi(vA.y);
      acc[4] += bflo(vA.z); acc[5] += bfhi(vA.z);
      acc[6] += bflo(vA.w); acc[7] += bfhi(vA.w);
      acc[0] += bflo(vB.x); acc[1] += bfhi(vB.x);
      acc[2] += bflo(vB.y); acc[3] += bfhi(vB.y);
      acc[4] += bflo(vB.z); acc[5] += bfhi(vB.z);
      acc[6] += bflo(vB.w); acc[7] += bfhi(vB.w);
    }
    if (i + 8 <= o1) {
      int s = esrc[i + r];
      uint4 v = *(const uint4*)(featb + s * 64 + c * 8);
      acc[0] += bflo(v.x); acc[1] += bfhi(v.x);
      acc[2] += bflo(v.y); acc[3] += bfhi(v.y);
      acc[4] += bflo(v.z); acc[5] += bfhi(v.z);
      acc[6] += bflo(v.w); acc[7] += bfhi(v.w);
      i += 8;
    }
    if (i < o1) {
      int e = i + r;
      if (e < o1) {
        int s = esrc[e];
        uint4 v = *(const uint4*)(featb + s * 64 + c * 8);
        acc[0] += bflo(v.x); acc[1] += bfhi(v.x);
        acc[2] += bflo(v.y); acc[3] += bfhi(v.y);
        acc[4] += bflo(v.z); acc[5] += bfhi(v.z);
        acc[6] += bflo(v.w); acc[7] += bfhi(v.w);
      }
    }
    #pragma unroll
    for (int m = 8; m <= 32; m <<= 1)
      #pragma unroll
      for (int q = 0; q < 8; q++) acc[q] += __shfl_xor(acc[q], m);

    const int dg = o1 - o0;
    const float inv = (dg > 0) ? (1.0f / (float)dg) : 0.f;
    if (r == 0) {
      unsigned d0 = ((unsigned)f2bf(acc[1] * inv) << 16) | f2bf(acc[0] * inv);
      unsigned d1 = ((unsigned)f2bf(acc[3] * inv) << 16) | f2bf(acc[2] * inv);
      unsigned d2 = ((unsigned)f2bf(acc[5] * inv) << 16) | f2bf(acc[4] * inv);
      unsigned d3 = ((unsigned)f2bf(acc[7] * inv) << 16) | f2bf(acc[6] * inv);
      *(uint4*)(lw + j * 64 + ((c ^ (j & 7)) << 3)) = make_uint4(d0, d1, d2, d3);
    }
  }

  // same-wave LDS RAW: DS pipe is per-wave in-order; pin compiler ordering and
  // keep the weight-fragment loads from being scheduled up into the agg phase
  __builtin_amdgcn_wave_barrier();
  asm volatile("" ::: "memory");

  // ---- xform phase: 16x64 @ 64x64 via 16 MFMAs ----
  const int col = lane & 15, rr = lane >> 4;
  const int m = t * 16 + col;
  short8 as0 = *(const short8*)(featb + m * 64 + rr * 8);
  short8 as1 = *(const short8*)(featb + m * 64 + 32 + rr * 8);
  short8 aa0 = *(const short8*)(lw + col * 64 + ((rr ^ (col & 7)) << 3));
  short8 aa1 = *(const short8*)(lw + col * 64 + (((rr + 4) ^ (col & 7)) << 3));

  #pragma unroll
  for (int nt = 0; nt < 4; nt++) {
    short8 bs0 = *(const short8*)(wfS + ((0 * 4 + nt) * 64 + lane) * 8);
    short8 bs1 = *(const short8*)(wfS + ((1 * 4 + nt) * 64 + lane) * 8);
    short8 bn0 = *(const short8*)(wfN + ((0 * 4 + nt) * 64 + lane) * 8);
    short8 bn1 = *(const short8*)(wfN + ((1 * 4 + nt) * 64 + lane) * 8);
    float bvn = bias[nt * 16 + col];
    float4v cfr = {bvn, bvn, bvn, bvn};
    cfr = __builtin_amdgcn_mfma_f32_16x16x32_bf16(as0, bs0, cfr, 0, 0, 0);
    cfr = __builtin_amdgcn_mfma_f32_16x16x32_bf16(as1, bs1, cfr, 0, 0, 0);
    cfr = __builtin_amdgcn_mfma_f32_16x16x32_bf16(aa0, bn0, cfr, 0, 0, 0);
    cfr = __builtin_amdgcn_mfma_f32_16x16x32_bf16(aa1, bn1, cfr, 0, 0, 0);
    #pragma unroll
    for (int r2 = 0; r2 < 4; r2++) {
      int row = t * 16 + rr * 4 + r2;
      float v = cfr[r2];
      if (RELU) v = fmaxf(v, 0.f);
      if (OUT_BF) outb[row * 64 + nt * 16 + col] = f2bf(v);
      else        outf[row * 64 + nt * 16 + col] = v;
    }
  }
}

// ---- launch ----------------------------------------------------------------

extern "C" void kernel_launch(void* const* d_in, const int* in_sizes, int n_in,
                              void* d_out, int out_size, void* d_ws, size_t ws_size,
                              hipStream_t stream) {
  const float* x   = (const float*)d_in[0];
  const int*   src = (const int*)d_in[1];
  const int*   dst = (const int*)d_in[2];
  const float* Ws1 = (const float*)d_in[3];
  const float* Wn1 = (const float*)d_in[4];
  const float* b1  = (const float*)d_in[5];
  const float* Ws2 = (const float*)d_in[6];
  const float* Wn2 = (const float*)d_in[7];
  const float* b2  = (const float*)d_in[8];

  char* ws = (char*)d_ws;
  int*            blkCnt   = (int*)(ws + 0);          // NBKT*256 ints
  int*            bktTot   = (int*)(ws + 262144);     // NBKT ints
  int*            bktStart = (int*)(ws + 266240);     // NBKT ints
  unsigned short* wf       = (unsigned short*)(ws + 270336);   // 32 KB
  int*            binned   = (int*)(ws + 303104);     // E ints (6.4 MB)
  int*            off      = (int*)(ws + 6703104);    // N+1 ints
  int*            esrc     = (int*)(ws + 7103488);    // E ints (6.4 MB)
  unsigned short* xbf      = (unsigned short*)(ws + 13503488);  // N*64 bf16
  unsigned short* hbf      = (unsigned short*)(ws + 26303488);  // N*64 bf16

  kA_count<<<256, 256, 0, stream>>>(dst, blkCnt);
  kA_scan1<<<NBKT, 256, 0, stream>>>(blkCnt, bktTot);
  kA_scan2<<<1, 64, 0, stream>>>(bktTot, bktStart);
  kA_scatter<<<256, 256, 0, stream>>>(src, dst, blkCnt, bktStart, binned);
  k_sort<<<NBKT, 256, 0, stream>>>(binned, bktStart, bktTot, off, esrc);

  k_prep<<<NT_TILES + 4, 256, 0, stream>>>(x, xbf, Ws1, Wn1, Ws2, Wn2, wf);

  k_fused<true, true><<<1563, 256, 0, stream>>>(xbf, off, esrc, wf + 0 * 4096,
                                                wf + 1 * 4096, b1, nullptr, hbf);
  k_fused<false, false><<<1563, 256, 0, stream>>>(hbf, off, esrc, wf + 2 * 4096,
                                                  wf + 3 * 4096, b2, (float*)d_out, nullptr);
}

// Round 2
// 199.729 us; speedup vs baseline: 1.2159x; 1.1945x over previous
//
#include <hip/hip_runtime.h>

#define N_NODES 100000
#define N_EDGES 1600000
#define NBKT 196          // ceil(100000 / 512)
#define BKT_SHIFT 9
#define BKT_MASK 511
#define NT_TILES 6250     // N_NODES / 16
#define CNT_BLOCKS 256

typedef __attribute__((ext_vector_type(8))) short short8;
typedef __attribute__((ext_vector_type(4))) float float4v;

__device__ __forceinline__ unsigned short f2bf(float f) {  // RNE
  unsigned u = __float_as_uint(f);
  return (unsigned short)((u + 0x7fffu + ((u >> 16) & 1u)) >> 16);
}
__device__ __forceinline__ float bflo(unsigned d) { return __uint_as_float(d << 16); }
__device__ __forceinline__ float bfhi(unsigned d) { return __uint_as_float(d & 0xffff0000u); }

__device__ __forceinline__ void acc_add(float a[8], uint4 v) {
  a[0] += bflo(v.x); a[1] += bfhi(v.x);
  a[2] += bflo(v.y); a[3] += bfhi(v.y);
  a[4] += bflo(v.z); a[5] += bfhi(v.z);
  a[6] += bflo(v.w); a[7] += bfhi(v.w);
}
__device__ __forceinline__ void acc_fma(float a[8], uint4 v, float m) {
  a[0] = fmaf(m, bflo(v.x), a[0]); a[1] = fmaf(m, bfhi(v.x), a[1]);
  a[2] = fmaf(m, bflo(v.y), a[2]); a[3] = fmaf(m, bfhi(v.y), a[3]);
  a[4] = fmaf(m, bflo(v.z), a[4]); a[5] = fmaf(m, bfhi(v.z), a[5]);
  a[6] = fmaf(m, bflo(v.w), a[6]); a[7] = fmaf(m, bfhi(v.w), a[7]);
}

// ---- merged: f32->bf16 cvt + weight pre-swizzle + edge bucket count --------

__global__ void k_prep_count(const float* __restrict__ in, unsigned short* __restrict__ outb,
                             const float* __restrict__ W0, const float* __restrict__ W1,
                             const float* __restrict__ W2, const float* __restrict__ W3,
                             unsigned short* __restrict__ F,
                             const int* __restrict__ dst, int* __restrict__ blkCnt) {
  __shared__ int hist[NBKT];
  const int bid = blockIdx.x;
  if (bid < NT_TILES) {
    // cvt: 6250 blocks x 256 threads x float4 == exactly N_NODES*64 floats
    int i = bid * 256 + threadIdx.x;
    float4 v = ((const float4*)in)[i];
    unsigned d0 = ((unsigned)f2bf(v.y) << 16) | f2bf(v.x);
    unsigned d1 = ((unsigned)f2bf(v.w) << 16) | f2bf(v.z);
    ((uint2*)outb)[i] = make_uint2(d0, d1);
    return;
  }
  if (bid < NT_TILES + 4) {
    // weight pre-swizzle into MFMA B-fragment order
    if (threadIdx.x >= 64) return;
    const int wsel = bid - NT_TILES;
    const float* W = (wsel == 0) ? W0 : (wsel == 1) ? W1 : (wsel == 2) ? W2 : W3;
    unsigned short* out = F + wsel * 4096;
    int lane = threadIdx.x;
    int col = lane & 15, kr = lane >> 4;
    #pragma unroll
    for (int kc = 0; kc < 2; kc++)
      #pragma unroll
      for (int nt = 0; nt < 4; nt++) {
        unsigned d[4];
        #pragma unroll
        for (int jj = 0; jj < 4; jj++) {
          float w0 = W[(kc * 32 + kr * 8 + 2 * jj)     * 64 + nt * 16 + col];
          float w1 = W[(kc * 32 + kr * 8 + 2 * jj + 1) * 64 + nt * 16 + col];
          d[jj] = ((unsigned)f2bf(w1) << 16) | f2bf(w0);
        }
        uint4* p = (uint4*)(out + ((kc * 4 + nt) * 64 + lane) * 8);
        *p = make_uint4(d[0], d[1], d[2], d[3]);
      }
    return;
  }
  // edge bucket count (256 trailing blocks)
  const int cb = bid - NT_TILES - 4;
  for (int t = threadIdx.x; t < NBKT; t += 256) hist[t] = 0;
  __syncthreads();
  const int chunk = N_EDGES / CNT_BLOCKS;   // 6250 exactly
  const int e0 = cb * chunk;
  const int e1 = e0 + chunk;
  for (int e = e0 + threadIdx.x; e < e1; e += 256)
    atomicAdd(&hist[dst[e] >> BKT_SHIFT], 1);
  __syncthreads();
  for (int t = threadIdx.x; t < NBKT; t += 256)
    blkCnt[t * 256 + cb] = hist[t];
}

__global__ void kA_scan1(int* __restrict__ blkCnt, int* __restrict__ bktTot) {
  const int b = blockIdx.x;
  const int tid = threadIdx.x, lane = tid & 63, w = tid >> 6;
  int v = blkCnt[b * 256 + tid];
  int inc = v;
  #pragma unroll
  for (int d = 1; d < 64; d <<= 1) { int y = __shfl_up(inc, d); if (lane >= d) inc += y; }
  __shared__ int wtot[4];
  if (lane == 63) wtot[w] = inc;
  __syncthreads();
  int base = 0;
  for (int j = 0; j < w; j++) base += wtot[j];
  blkCnt[b * 256 + tid] = base + inc - v;
  if (tid == 255) bktTot[b] = base + inc;
}

__global__ void kA_scatter(const int* __restrict__ src, const int* __restrict__ dst,
                           const int* __restrict__ blkCnt, const int* __restrict__ bktTot,
                           int* __restrict__ binned) {
  __shared__ int bs[NBKT];
  __shared__ int curb[NBKT];
  const int tid = threadIdx.x;
  // in-block exclusive scan of bktTot -> bs (replaces the old kA_scan2 kernel)
  if (tid < 64) {
    int running = 0;
    for (int base = 0; base < NBKT; base += 64) {
      int i = base + tid;
      int v = (i < NBKT) ? bktTot[i] : 0;
      int inc = v;
      #pragma unroll
      for (int d = 1; d < 64; d <<= 1) { int y = __shfl_up(inc, d); if (tid >= d) inc += y; }
      if (i < NBKT) bs[i] = running + inc - v;
      running += __shfl(inc, 63);
    }
  }
  __syncthreads();
  for (int t = tid; t < NBKT; t += 256)
    curb[t] = bs[t] + blkCnt[t * 256 + blockIdx.x];
  __syncthreads();
  const int chunk = N_EDGES / CNT_BLOCKS;
  const int e0 = blockIdx.x * chunk;
  const int e1 = e0 + chunk;
  for (int e = e0 + tid; e < e1; e += 256) {
    int d = dst[e];
    int s = src[e];
    int b = d >> BKT_SHIFT;
    int p = atomicAdd(&curb[b], 1);
    binned[p] = s | ((d & BKT_MASK) << 17);   // src:17 bits | dlocal:9 bits
  }
}

// ---- merged counting sort (512 threads: 1 node counter per thread) ---------

__global__ void k_sort(const int* __restrict__ binned, const int* __restrict__ bktTot,
                       int* __restrict__ off, int* __restrict__ esrc) {
  const int b = blockIdx.x;
  const int tid = threadIdx.x, lane = tid & 63, w = tid >> 6;
  __shared__ int cnt[512];
  __shared__ int pos[512];
  __shared__ int wtot[8];
  __shared__ int s0sh;
  cnt[tid] = 0;
  // prefix of bucket totals up to b (replaces old bktStart read)
  if (tid < 64) {
    int sum = 0;
    for (int i = tid; i < b; i += 64) sum += bktTot[i];
    #pragma unroll
    for (int m = 1; m < 64; m <<= 1) sum += __shfl_xor(sum, m);
    if (tid == 0) s0sh = sum;
  }
  __syncthreads();
  const int s0 = s0sh, ne = bktTot[b];
  for (int i = tid; i < ne; i += 512)
    atomicAdd(&cnt[binned[s0 + i] >> 17], 1);
  __syncthreads();
  // scan 512 counters, one per thread, across 8 waves
  int c = cnt[tid];
  int inc = c;
  #pragma unroll
  for (int d = 1; d < 64; d <<= 1) { int y = __shfl_up(inc, d); if (lane >= d) inc += y; }
  if (lane == 63) wtot[w] = inc;
  __syncthreads();
  int base = s0;
  for (int j = 0; j < w; j++) base += wtot[j];
  int ex = base + inc - c;   // global edge offset of node (b<<9)+tid
  pos[tid] = ex;
  int n0 = (b << BKT_SHIFT) + tid;
  if (n0 < N_NODES) off[n0] = ex;
  if (b == NBKT - 1 && tid == 0) off[N_NODES] = N_EDGES;
  __syncthreads();
  for (int i = tid; i < ne; i += 512) {
    int pe = binned[s0 + i];
    int p = atomicAdd(&pos[pe >> 17], 1);
    esrc[p] = pe & 0x1FFFF;
  }
}

// ---- fused per-layer: mean-aggregate 16 nodes -> LDS -> MFMA transform -----
// agg: 8 lanes per node (feature-block ownership) -> no cross-lane reduce,
// 8 nodes in flight per wave, 4-edge unroll for MLP.

template <bool RELU, bool OUT_BF>
__global__ void k_fused(const unsigned short* __restrict__ featb,
                        const int* __restrict__ off, const int* __restrict__ esrc,
                        const unsigned short* __restrict__ wfS,
                        const unsigned short* __restrict__ wfN,
                        const float* __restrict__ bias,
                        float* __restrict__ outf, unsigned short* __restrict__ outb) {
  // per-wave 16x64 bf16 agg tile, XOR-swizzled in 16B blocks:
  // row j, block bk stored at slot bk^(j&7)
  __shared__ unsigned short aggl[4][16 * 64];
  const int tid = threadIdx.x;
  const int lane = tid & 63;
  const int wslot = tid >> 6;
  const int t = (blockIdx.x * blockDim.x + tid) >> 6;   // one 16-node tile per wave
  if (t >= NT_TILES) return;

  unsigned short* lw = &aggl[wslot][0];
  const int n = lane >> 3;   // node slot (8 nodes in parallel)
  const int h = lane & 7;    // feature block (8 bf16 = 16B), exclusive ownership

  #pragma unroll
  for (int half = 0; half < 2; ++half) {
    const int row = half * 8 + n;          // tile-local row 0..15
    const int node = t * 16 + row;
    const int o0 = off[node];
    const int o1 = off[node + 1];
    float a[8];
    #pragma unroll
    for (int q = 0; q < 8; q++) a[q] = 0.f;

    int i = o0;
    for (; i + 4 <= o1; i += 4) {          // 4 outstanding gathers per lane
      int s0 = esrc[i], s1 = esrc[i + 1], s2 = esrc[i + 2], s3 = esrc[i + 3];
      uint4 v0 = *(const uint4*)(featb + s0 * 64 + h * 8);
      uint4 v1 = *(const uint4*)(featb + s1 * 64 + h * 8);
      uint4 v2 = *(const uint4*)(featb + s2 * 64 + h * 8);
      uint4 v3 = *(const uint4*)(featb + s3 * 64 + h * 8);
      acc_add(a, v0); acc_add(a, v1); acc_add(a, v2); acc_add(a, v3);
    }
    if (i < o1) {                          // masked quad: 1..3 remaining edges
      int last = o1 - 1;
      int e1 = min(i + 1, last), e2 = min(i + 2, last);
      float m1 = (i + 1 < o1) ? 1.f : 0.f;
      float m2 = (i + 2 < o1) ? 1.f : 0.f;
      int s0 = esrc[i], s1 = esrc[e1], s2 = esrc[e2];
      uint4 v0 = *(const uint4*)(featb + s0 * 64 + h * 8);
      uint4 v1 = *(const uint4*)(featb + s1 * 64 + h * 8);
      uint4 v2 = *(const uint4*)(featb + s2 * 64 + h * 8);
      acc_add(a, v0); acc_fma(a, v1, m1); acc_fma(a, v2, m2);
    }

    const int dg = o1 - o0;
    const float inv = (dg > 0) ? (1.0f / (float)dg) : 0.f;
    unsigned d0 = ((unsigned)f2bf(a[1] * inv) << 16) | f2bf(a[0] * inv);
    unsigned d1 = ((unsigned)f2bf(a[3] * inv) << 16) | f2bf(a[2] * inv);
    unsigned d2 = ((unsigned)f2bf(a[5] * inv) << 16) | f2bf(a[4] * inv);
    unsigned d3 = ((unsigned)f2bf(a[7] * inv) << 16) | f2bf(a[6] * inv);
    *(uint4*)(lw + row * 64 + ((h ^ (row & 7)) << 3)) = make_uint4(d0, d1, d2, d3);
  }

  // same-wave LDS RAW: DS pipe is per-wave in-order; pin compiler ordering
  __builtin_amdgcn_wave_barrier();
  asm volatile("" ::: "memory");

  // ---- xform phase: 16x64 @ 64x64 via 16 MFMAs ----
  const int col = lane & 15, rr = lane >> 4;
  const int m = t * 16 + col;
  short8 as0 = *(const short8*)(featb + m * 64 + rr * 8);
  short8 as1 = *(const short8*)(featb + m * 64 + 32 + rr * 8);
  short8 aa0 = *(const short8*)(lw + col * 64 + ((rr ^ (col & 7)) << 3));
  short8 aa1 = *(const short8*)(lw + col * 64 + (((rr + 4) ^ (col & 7)) << 3));

  #pragma unroll
  for (int nt = 0; nt < 4; nt++) {
    short8 bs0 = *(const short8*)(wfS + ((0 * 4 + nt) * 64 + lane) * 8);
    short8 bs1 = *(const short8*)(wfS + ((1 * 4 + nt) * 64 + lane) * 8);
    short8 bn0 = *(const short8*)(wfN + ((0 * 4 + nt) * 64 + lane) * 8);
    short8 bn1 = *(const short8*)(wfN + ((1 * 4 + nt) * 64 + lane) * 8);
    float bvn = bias[nt * 16 + col];
    float4v cfr = {bvn, bvn, bvn, bvn};
    cfr = __builtin_amdgcn_mfma_f32_16x16x32_bf16(as0, bs0, cfr, 0, 0, 0);
    cfr = __builtin_amdgcn_mfma_f32_16x16x32_bf16(as1, bs1, cfr, 0, 0, 0);
    cfr = __builtin_amdgcn_mfma_f32_16x16x32_bf16(aa0, bn0, cfr, 0, 0, 0);
    cfr = __builtin_amdgcn_mfma_f32_16x16x32_bf16(aa1, bn1, cfr, 0, 0, 0);
    #pragma unroll
    for (int r2 = 0; r2 < 4; r2++) {
      int row = t * 16 + rr * 4 + r2;
      float v = cfr[r2];
      if (RELU) v = fmaxf(v, 0.f);
      if (OUT_BF) outb[row * 64 + nt * 16 + col] = f2bf(v);
      else        outf[row * 64 + nt * 16 + col] = v;
    }
  }
}

// ---- launch ----------------------------------------------------------------

extern "C" void kernel_launch(void* const* d_in, const int* in_sizes, int n_in,
                              void* d_out, int out_size, void* d_ws, size_t ws_size,
                              hipStream_t stream) {
  const float* x   = (const float*)d_in[0];
  const int*   src = (const int*)d_in[1];
  const int*   dst = (const int*)d_in[2];
  const float* Ws1 = (const float*)d_in[3];
  const float* Wn1 = (const float*)d_in[4];
  const float* b1  = (const float*)d_in[5];
  const float* Ws2 = (const float*)d_in[6];
  const float* Wn2 = (const float*)d_in[7];
  const float* b2  = (const float*)d_in[8];

  char* ws = (char*)d_ws;
  int*            blkCnt   = (int*)(ws + 0);          // NBKT*256 ints
  int*            bktTot   = (int*)(ws + 262144);     // NBKT ints
  unsigned short* wf       = (unsigned short*)(ws + 270336);   // 32 KB
  int*            binned   = (int*)(ws + 303104);     // E ints (6.4 MB)
  int*            off      = (int*)(ws + 6703104);    // N+1 ints
  int*            esrc     = (int*)(ws + 7103488);    // E ints (6.4 MB)
  unsigned short* xbf      = (unsigned short*)(ws + 13503488);  // N*64 bf16
  unsigned short* hbf      = (unsigned short*)(ws + 26303488);  // N*64 bf16

  k_prep_count<<<NT_TILES + 4 + CNT_BLOCKS, 256, 0, stream>>>(
      x, xbf, Ws1, Wn1, Ws2, Wn2, wf, dst, blkCnt);
  kA_scan1<<<NBKT, 256, 0, stream>>>(blkCnt, bktTot);
  kA_scatter<<<CNT_BLOCKS, 256, 0, stream>>>(src, dst, blkCnt, bktTot, binned);
  k_sort<<<NBKT, 512, 0, stream>>>(binned, bktTot, off, esrc);

  k_fused<true, true><<<1563, 256, 0, stream>>>(xbf, off, esrc, wf + 0 * 4096,
                                                wf + 1 * 4096, b1, nullptr, hbf);
  k_fused<false, false><<<1563, 256, 0, stream>>>(hbf, off, esrc, wf + 2 * 4096,
                                                  wf + 3 * 4096, b2, (float*)d_out, nullptr);
}